// Round 1
// baseline (88.280 us; speedup 1.0000x reference)
//
#include <hip/hip_runtime.h>

#define B    512
#define NBG  10000
#define F    32
#define H    128

// ---------------- Kernel 1: per-row MLP -> babs[b][f] = |b_vec[b][f]| ----------------
__global__ __launch_bounds__(128) void mlp_kernel(
    const float* __restrict__ X,
    const float* __restrict__ W0, const float* __restrict__ b0,
    const float* __restrict__ W1, const float* __restrict__ b1,
    const float* __restrict__ Wout, const float* __restrict__ bout,
    float* __restrict__ babs)
{
    __shared__ float xrow[F];
    __shared__ float h0[H];
    __shared__ float h1[H];

    const int b = blockIdx.x;
    const int t = threadIdx.x;

    if (t < F) xrow[t] = X[b * F + t];
    __syncthreads();

    // layer 0: [F] -> [H], one neuron per thread
    float acc = b0[t];
    #pragma unroll
    for (int f = 0; f < F; ++f) acc += xrow[f] * W0[f * H + t];
    h0[t] = fmaxf(acc, 0.f);
    __syncthreads();

    // layer 1: [H] -> [H]
    acc = b1[t];
    #pragma unroll 8
    for (int j = 0; j < H; ++j) acc += h0[j] * W1[j * H + t];
    h1[t] = fmaxf(acc, 0.f);
    __syncthreads();

    // head: [H] -> [F], threads 0..31
    if (t < F) {
        float a = bout[t];
        #pragma unroll 8
        for (int j = 0; j < H; ++j) a += h1[j] * Wout[j * F + t];
        babs[b * F + t] = fabsf(a);
    }
}

// ---------------- Kernel 2: NW partial sums ----------------
// Block: 512 threads = 8 waves; wave w owns batch row b = blockIdx.x*8 + w.
// Grid.y splits the 10000 background points into NC chunks.
#define WPB   8
#define NC    16
#define CHUNK 640   // 16 * 640 = 10240 >= 10000

__global__ __launch_bounds__(512) void nw_partial(
    const float* __restrict__ X,
    const float* __restrict__ xbg,
    const float* __restrict__ ybg,
    const float* __restrict__ babs,
    float* __restrict__ psw,
    float* __restrict__ pswy)
{
    const int wid  = threadIdx.x >> 6;
    const int lane = threadIdx.x & 63;
    const int b    = blockIdx.x * WPB + wid;
    const int n0   = blockIdx.y * CHUNK;
    const int nEnd = min(n0 + CHUNK, NBG);

    // X row and |b_vec| row in registers (wave-uniform values; 64 VGPRs)
    float xq[F], bv[F];
    const float4* xr = (const float4*)(X + b * F);
    const float4* br = (const float4*)(babs + b * F);
    #pragma unroll
    for (int q = 0; q < F / 4; ++q) {
        float4 xv = xr[q];
        float4 bb = br[q];
        xq[4*q+0] = xv.x; xq[4*q+1] = xv.y; xq[4*q+2] = xv.z; xq[4*q+3] = xv.w;
        bv[4*q+0] = bb.x; bv[4*q+1] = bb.y; bv[4*q+2] = bb.z; bv[4*q+3] = bb.w;
    }

    float sw = 0.f, swy = 0.f;
    for (int n = n0 + lane; n < nEnd; n += 64) {
        const float4* xb = (const float4*)(xbg + n * F);
        float d = 0.f;
        #pragma unroll
        for (int q = 0; q < F / 4; ++q) {
            float4 v = xb[q];
            d += bv[4*q+0] * fabsf(xq[4*q+0] - v.x);
            d += bv[4*q+1] * fabsf(xq[4*q+1] - v.y);
            d += bv[4*q+2] * fabsf(xq[4*q+2] - v.z);
            d += bv[4*q+3] * fabsf(xq[4*q+3] - v.w);
        }
        const float w = __expf(-d);
        sw  += w;
        swy += w * ybg[n];
    }

    // wave reduction (64 lanes)
    #pragma unroll
    for (int off = 32; off > 0; off >>= 1) {
        sw  += __shfl_down(sw,  off);
        swy += __shfl_down(swy, off);
    }
    if (lane == 0) {
        psw [b * NC + blockIdx.y] = sw;
        pswy[b * NC + blockIdx.y] = swy;
    }
}

// ---------------- Kernel 3: combine partials, normalize ----------------
__global__ __launch_bounds__(B) void nw_final(
    const float* __restrict__ psw,
    const float* __restrict__ pswy,
    float* __restrict__ out)
{
    const int b = threadIdx.x;
    float sw = 0.f, swy = 0.f;
    #pragma unroll
    for (int c = 0; c < NC; ++c) {
        sw  += psw [b * NC + c];
        swy += pswy[b * NC + c];
    }
    out[b] = swy / sw;
}

extern "C" void kernel_launch(void* const* d_in, const int* in_sizes, int n_in,
                              void* d_out, int out_size, void* d_ws, size_t ws_size,
                              hipStream_t stream)
{
    const float* X    = (const float*)d_in[0];
    const float* xbg  = (const float*)d_in[1];
    const float* ybg  = (const float*)d_in[2];
    const float* W0   = (const float*)d_in[3];
    const float* b0   = (const float*)d_in[4];
    const float* W1   = (const float*)d_in[5];
    const float* b1   = (const float*)d_in[6];
    const float* Wout = (const float*)d_in[7];
    const float* bout = (const float*)d_in[8];
    float* out = (float*)d_out;

    float* babs = (float*)d_ws;          // B*F floats   = 64 KiB
    float* psw  = babs + B * F;          // B*NC floats  = 32 KiB
    float* pswy = psw + B * NC;          // B*NC floats  = 32 KiB

    mlp_kernel<<<B, H, 0, stream>>>(X, W0, b0, W1, b1, Wout, bout, babs);
    nw_partial<<<dim3(B / WPB, NC), 512, 0, stream>>>(X, xbg, ybg, babs, psw, pswy);
    nw_final<<<1, B, 0, stream>>>(psw, pswy, out);
}